// Round 9
// baseline (34.992 us; speedup 1.0000x reference)
//
#include <hip/hip_runtime.h>

// DTYPES SETTLED (R6 post-mortem, executed-path evidence; R7/R8 passed on this path):
//   boxes = fp32 (float*), mask = int32 (int*), out = fp32 (float*).
//
// R8 lesson: register-resident load batching is unachievable (VGPR stayed 40 despite
// sched_barrier + launch_bounds). Model: concurrency-limited, BW = bytes_in_flight/latency.
// R9: global_load_lds staging -> concurrency without VGPRs; 18.4KB LDS -> 8 blocks/CU.

constexpr float EPSF      = 1e-9f;
constexpr float HALF_PI_F = 1.5707963267948966f;
constexpr float INV_PI2_4 = 0.40528473456935109f;   // 4 / pi^2

__device__ __forceinline__ float fast_rcp(float x) { return __builtin_amdgcn_rcpf(x); }

__device__ __forceinline__ void glds16(const void* g, void* l) {
    __builtin_amdgcn_global_load_lds((const __attribute__((address_space(1))) void*)g,
                                     (__attribute__((address_space(3))) void*)l, 16, 0, 0);
}
__device__ __forceinline__ void glds4(const void* g, void* l) {
    __builtin_amdgcn_global_load_lds((const __attribute__((address_space(1))) void*)g,
                                     (__attribute__((address_space(3))) void*)l, 4, 0, 0);
}

// minimax atan on [0,1], extended by atan(x) = pi/2 - atan(1/x); max err ~1e-6
// (validated within harness threshold by R1/R2/R4/R7/R8 passes)
__device__ __forceinline__ float fast_atan(float t) {
    float a = fabsf(t);
    bool big = a > 1.0f;
    float x = big ? fast_rcp(a) : a;
    float s = x * x;
    float p = -0.0117212f;
    p = fmaf(p, s, 0.05265332f);
    p = fmaf(p, s, -0.11643287f);
    p = fmaf(p, s, 0.19354346f);
    p = fmaf(p, s, -0.33262347f);
    p = fmaf(p, s, 0.99997726f);
    p = x * p;
    float r = big ? (HALF_PI_F - p) : p;
    return copysignf(r, t);
}

__device__ __forceinline__ float ciou_one(float x1a, float y1a, float x2a, float y2a,
                                          float x1b, float y1b, float x2b, float y2b) {
    float xmin = fmaxf(x1a, x1b), ymin = fmaxf(y1a, y1b);
    float xmax = fminf(x2a, x2b), ymax = fminf(y2a, y2b);
    float inter = fmaxf(xmax - xmin, 0.0f) * fmaxf(ymax - ymin, 0.0f);
    float wa = x2a - x1a, ha = y2a - y1a;
    float wb = x2b - x1b, hb = y2b - y1b;
    float uni = wa * ha + wb * hb - inter;
    float iou = inter * fast_rcp(uni + EPSF);
    float dx = (x1a + x2a) - (x1b + x2b);
    float dy = (y1a + y2a) - (y1b + y2b);
    float cd = 0.25f * (dx * dx + dy * dy);
    float cw = fmaxf(x2a, x2b) - fminf(x1a, x1b);
    float ch = fmaxf(y2a, y2b) - fminf(y1a, y1b);
    float diag = cw * cw + ch * ch + EPSF;
    // atan(wa/ha') - atan(wb/hb') == atan((wa*hb' - wb*ha')/(ha'*hb' + wa*wb));
    // both ratios >= 0, so branch-free exact, result in (-pi/2, pi/2)
    float ha_ = ha + EPSF, hb_ = hb + EPSF;
    float at = fast_atan((wa * hb_ - wb * ha_) * fast_rcp(ha_ * hb_ + wa * wb + EPSF));
    float v = INV_PI2_4 * at * at;
    float av = v * v * fast_rcp(v - iou + 1.0f + EPSF);   // alpha * v
    return iou - cd * fast_rcp(diag) - av;
}

// Main: 512-box tile per block staged to LDS via global_load_lds (async DMA, no VGPR
// cost, compiler cannot sink it). LDS dest = wave-uniform base + lane*size (layout
// rule). 18.4KB LDS -> 8 blocks/CU; co-resident blocks pipeline DMA vs compute.
__global__ __launch_bounds__(256) void ciou_main(const float4* __restrict__ pred4,
                                                 const float4* __restrict__ targ4,
                                                 const int* __restrict__ mask,
                                                 float* __restrict__ out, int n,
                                                 float* __restrict__ part_loss,
                                                 float* __restrict__ part_cnt) {
    __shared__ float4 spred[512];   // 8 KB
    __shared__ float4 starg[512];   // 8 KB
    __shared__ int    smask[512];   // 2 KB

    const int i = threadIdx.x;
    const int w = i >> 6, l = i & 63;
    float lsum = 0.0f;
    int cnt = 0;

    for (int base = blockIdx.x * 512; base < n; base += gridDim.x * 512) {
        if (base + 512 <= n) {   // full tile (the only path for the bench shape)
            // async stage: wave w stages box-chunks 2w and 2w+1 (64 boxes each)
            const int c0 = 2 * w, c1 = c0 + 1;
            glds16(pred4 + base + 64 * c0 + l, &spred[64 * c0]);
            glds16(pred4 + base + 64 * c1 + l, &spred[64 * c1]);
            glds16(targ4 + base + 64 * c0 + l, &starg[64 * c0]);
            glds16(targ4 + base + 64 * c1 + l, &starg[64 * c1]);
            glds4 (mask  + base + 64 * c0 + l, &smask[64 * c0]);
            glds4 (mask  + base + 64 * c1 + l, &smask[64 * c1]);
            __syncthreads();   // compiler emits s_waitcnt vmcnt(0) before s_barrier

            #pragma unroll
            for (int k = 0; k < 2; ++k) {
                const int t = 256 * k + i;
                float4 p = spred[t];
                float4 q = starg[t];
                bool valid = smask[t] != 0;
                float mf = valid ? 1.0f : 0.0f;
                float c = ciou_one(p.x, p.y, p.z, p.w, q.x, q.y, q.z, q.w);
                out[1 + base + t] = c * mf;
                lsum += (1.0f - c) * mf;
                cnt += valid ? 1 : 0;
            }
            __syncthreads();   // protect LDS before next tile's DMA overwrites it
        } else {               // tail tile: direct global, per-element guard (no barrier)
            #pragma unroll
            for (int k = 0; k < 2; ++k) {
                int b = base + 256 * k + i;
                if (b < n) {
                    float4 p = pred4[b], q = targ4[b];
                    bool valid = mask[b] != 0;
                    float mf = valid ? 1.0f : 0.0f;
                    float c = ciou_one(p.x, p.y, p.z, p.w, q.x, q.y, q.z, q.w);
                    out[1 + b] = c * mf;
                    lsum += (1.0f - c) * mf;
                    cnt += valid ? 1 : 0;
                }
            }
        }
    }

    // block reduction: wave shfl, then cross-wave via LDS
    for (int off = 32; off > 0; off >>= 1) {
        lsum += __shfl_down(lsum, off);
        cnt  += __shfl_down(cnt, off);
    }
    __shared__ float sl[4];
    __shared__ int   sc[4];
    if ((i & 63) == 0) { sl[w] = lsum; sc[w] = cnt; }
    __syncthreads();
    if (i == 0) {
        part_loss[blockIdx.x] = sl[0] + sl[1] + sl[2] + sl[3];
        part_cnt[blockIdx.x]  = (float)(sc[0] + sc[1] + sc[2] + sc[3]);
    }
}

// Finalize: deterministic fixed-order double reduction; writes fp32 scalar to out[0].
__global__ __launch_bounds__(1024) void finalize_kernel(const float* __restrict__ part_loss,
                                                        const float* __restrict__ part_cnt,
                                                        float* __restrict__ out, int nb) {
    __shared__ double sl[1024], sc[1024];
    const int t = threadIdx.x;
    double l = 0.0, c = 0.0;
    for (int j = t; j < nb; j += 1024) {
        l += (double)part_loss[j];
        c += (double)part_cnt[j];
    }
    sl[t] = l; sc[t] = c;
    __syncthreads();
    for (int s = 512; s > 0; s >>= 1) {
        if (t < s) { sl[t] += sl[t + s]; sc[t] += sc[t + s]; }
        __syncthreads();
    }
    if (t == 0) out[0] = (float)(sl[0] / fmax(sc[0], 1.0));
}

extern "C" void kernel_launch(void* const* d_in, const int* in_sizes, int n_in,
                              void* d_out, int out_size, void* d_ws, size_t ws_size,
                              hipStream_t stream) {
    const float4* pred4 = (const float4*)d_in[0];
    const float4* targ4 = (const float4*)d_in[1];
    const int*    mask  = (const int*)d_in[2];
    float* out = (float*)d_out;
    int n = in_sizes[0] / 4;   // number of boxes

    int nblocks = (n + 511) / 512;                       // exact cover (8192 for bench shape)
    int ws_cap = (int)(ws_size / (2 * sizeof(float)));   // partials must fit in d_ws
    if (nblocks > ws_cap) nblocks = ws_cap;
    if (nblocks > 8192) nblocks = 8192;
    if (nblocks < 1) nblocks = 1;
    float* part_loss = (float*)d_ws;
    float* part_cnt  = part_loss + nblocks;

    ciou_main<<<nblocks, 256, 0, stream>>>(pred4, targ4, mask, out, n, part_loss, part_cnt);
    finalize_kernel<<<1, 1024, 0, stream>>>(part_loss, part_cnt, out, nblocks);
}